// Round 4
// baseline (310.969 us; speedup 1.0000x reference)
//
#include <hip/hip_runtime.h>

#define TEN 10

// Row partition over the 4 sub-lanes of a quad: {0,1,2},{3,4,5},{6,7,(8dup)},{8,9,(9dup)}.
// Slot 2 of subs 2,3 duplicates a real row (clamped) so code stays uniform; its
// LDS/global writes are suppressed (w2 == sub<2) so every row is written exactly once.

// ---------------------------------------------------------------------------
// In-LDS ordered tree product of 64 matrices (slots 0..63, stride 120 floats,
// rows at 12-float stride). Result lands in slot 0. Order-preserving pairing.
// ---------------------------------------------------------------------------
__device__ __forceinline__ void tree64(float* lds, int tid)
{
    const int q     = tid >> 2;
    const int sub   = tid & 3;
    const int rbase = (sub == 3) ? 8 : sub * 3;
    const int r0 = rbase, r1 = rbase + 1;
    const int r2 = (rbase + 2 > 9) ? 9 : rbase + 2;
    const bool w2 = (sub < 2);

    for (int np = 32; np >= 1; np >>= 1) {
        float c[3][TEN];
        if (q < np) {
            const float* A = lds + (2 * q) * 120;
            const float* B = lds + (2 * q + 1) * 120;
            float ar[3][TEN];
#pragma unroll
            for (int t = 0; t < 3; ++t) {
                const int rt = (t == 0) ? r0 : (t == 1) ? r1 : r2;
                const float4 a0 = reinterpret_cast<const float4*>(A + rt * 12)[0];
                const float4 a1 = reinterpret_cast<const float4*>(A + rt * 12)[1];
                const float2 a2 = reinterpret_cast<const float2*>(A + rt * 12 + 8)[0];
                ar[t][0]=a0.x; ar[t][1]=a0.y; ar[t][2]=a0.z; ar[t][3]=a0.w;
                ar[t][4]=a1.x; ar[t][5]=a1.y; ar[t][6]=a1.z; ar[t][7]=a1.w;
                ar[t][8]=a2.x; ar[t][9]=a2.y;
#pragma unroll
                for (int j = 0; j < TEN; ++j) c[t][j] = 0.0f;
            }
#pragma unroll
            for (int a = 0; a < TEN; ++a) {
                const float4 b0 = reinterpret_cast<const float4*>(B + a * 12)[0];
                const float4 b1 = reinterpret_cast<const float4*>(B + a * 12)[1];
                const float2 b2 = reinterpret_cast<const float2*>(B + a * 12 + 8)[0];
#pragma unroll
                for (int t = 0; t < 3; ++t) {
                    const float ma = ar[t][a];
                    c[t][0] = fmaf(ma, b0.x, c[t][0]);
                    c[t][1] = fmaf(ma, b0.y, c[t][1]);
                    c[t][2] = fmaf(ma, b0.z, c[t][2]);
                    c[t][3] = fmaf(ma, b0.w, c[t][3]);
                    c[t][4] = fmaf(ma, b1.x, c[t][4]);
                    c[t][5] = fmaf(ma, b1.y, c[t][5]);
                    c[t][6] = fmaf(ma, b1.z, c[t][6]);
                    c[t][7] = fmaf(ma, b1.w, c[t][7]);
                    c[t][8] = fmaf(ma, b2.x, c[t][8]);
                    c[t][9] = fmaf(ma, b2.y, c[t][9]);
                }
            }
        }
        __syncthreads();
        if (q < np) {
            float* C = lds + q * 120;
#pragma unroll
            for (int t = 0; t < 3; ++t) {
                const int rt = (t == 0) ? r0 : (t == 1) ? r1 : r2;
                if (t < 2 || w2) {
                    float* cr = C + rt * 12;
                    reinterpret_cast<float4*>(cr)[0] = make_float4(c[t][0], c[t][1], c[t][2], c[t][3]);
                    reinterpret_cast<float4*>(cr)[1] = make_float4(c[t][4], c[t][5], c[t][6], c[t][7]);
                    reinterpret_cast<float2*>(cr + 8)[0] = make_float2(c[t][8], c[t][9]);
                }
            }
        }
        __syncthreads();
    }
}

// ---------------------------------------------------------------------------
// Phase A: 4 lanes per chunk (16 chunks/wave, 64 chunks/block). Each lane
// builds ~3 rows of W_t (p-slice: 300 VGPRs) and owns ~3 rows of M, so the
// 400 B/step LDS read of W is amortized over 300 FMAs (2.5x less LDS traffic
// than the 10-lane scheme, which measured exactly at the 85 B/cyc LDS
// ceiling: 177 us). ~415 live VGPRs -> waves_per_eu(1,1): 512-reg budget,
// nothing below 1 wave/EU for the allocator to squeeze to. NO __launch_bounds__
// (R3 evidence: it capped the effective budget at ~128 regs despite (2,2)).
// Block = 256 thr = 4 waves = 1 CU; grid 256 = 1 block/CU.
// Epilogue: block tree-reduces its 64 chunk matrices -> 1 matrix per block.
// ---------------------------------------------------------------------------
__global__ __attribute__((amdgpu_flat_work_group_size(256, 256),
                          amdgpu_waves_per_eu(1, 1)))
void automaton_chunks(const float* __restrict__ x, const float* __restrict__ P,
                      float* __restrict__ outBlk, int L)
{
    // W staging: 64 chunks * 132 floats (chunk stride 132 => 4c mod 32 banks,
    // 2-way overlap across chunks = free; rows at 12-float stride, 16B aligned).
    // Reused afterwards as the 64-slot tree buffer (stride 120).
    __shared__ __align__(16) float lds[8448];

    const int tid  = threadIdx.x;
    const int wave = tid >> 6;
    const int lane = tid & 63;
    const int cl   = lane >> 2;           // chunk within wave, 0..15
    const int sub  = lane & 3;
    const int cib  = wave * 16 + cl;      // chunk within block, 0..63
    const long long chunk = (long long)blockIdx.x * 64 + cib;

    const int rbase = (sub == 3) ? 8 : sub * 3;
    const int r0 = rbase, r1 = rbase + 1;
    const int r2 = (rbase + 2 > 9) ? 9 : rbase + 2;
    const bool w2 = (sub < 2);

    // Loop-invariant P slices for this lane's rows: 300 floats.
    float p[3][TEN][TEN];
    {
        const int rr[3] = {r0, r1, r2};
#pragma unroll
        for (int t = 0; t < 3; ++t)
#pragma unroll
            for (int k = 0; k < TEN; ++k) {
                const float2* pp = reinterpret_cast<const float2*>(P + k * 100 + rr[t] * TEN);
                const float2 a0 = pp[0], a1 = pp[1], a2 = pp[2], a3 = pp[3], a4 = pp[4];
                p[t][k][0]=a0.x; p[t][k][1]=a0.y; p[t][k][2]=a1.x; p[t][k][3]=a1.y;
                p[t][k][4]=a2.x; p[t][k][5]=a2.y; p[t][k][6]=a3.x; p[t][k][7]=a3.y;
                p[t][k][8]=a4.x; p[t][k][9]=a4.y;
            }
    }

    // M rows (identity init).
    float m[3][TEN];
#pragma unroll
    for (int t = 0; t < 3; ++t) {
        const int rt = (t == 0) ? r0 : (t == 1) ? r1 : r2;
#pragma unroll
        for (int j = 0; j < TEN; ++j) m[t][j] = (j == rt) ? 1.0f : 0.0f;
    }

    float* wc = lds + cib * 132;
    const float2* xp = reinterpret_cast<const float2*>(x) + (size_t)chunk * L * 5;

    float2 nx0 = xp[0], nx1 = xp[1], nx2 = xp[2], nx3 = xp[3], nx4 = xp[4];
    xp += 5;

#pragma unroll 1
    for (int s = 0; s < L; ++s) {
        const float xv[TEN] = {nx0.x, nx0.y, nx1.x, nx1.y, nx2.x,
                               nx2.y, nx3.x, nx3.y, nx4.x, nx4.y};
        if (s + 1 < L) {
            nx0 = xp[0]; nx1 = xp[1]; nx2 = xp[2]; nx3 = xp[3]; nx4 = xp[4];
            xp += 5;
        }

        // Build this lane's W rows and publish (each row written exactly once).
#pragma unroll
        for (int t = 0; t < 3; ++t) {
            float w[TEN];
#pragma unroll
            for (int j = 0; j < TEN; ++j) {
                float acc = xv[0] * p[t][0][j];
#pragma unroll
                for (int k = 1; k < TEN; ++k) acc = fmaf(xv[k], p[t][k][j], acc);
                w[j] = acc;
            }
            const int rt = (t == 0) ? r0 : (t == 1) ? r1 : r2;
            if (t < 2 || w2) {
                float* wr = wc + rt * 12;
                reinterpret_cast<float4*>(wr)[0] = make_float4(w[0], w[1], w[2], w[3]);
                reinterpret_cast<float4*>(wr)[1] = make_float4(w[4], w[5], w[6], w[7]);
                reinterpret_cast<float2*>(wr + 8)[0] = make_float2(w[8], w[9]);
            }
        }
        __builtin_amdgcn_wave_barrier();  // same-wave DS ops are pipe-ordered

        // M <- M * W : one 400B read of W serves 300 FMAs.
        float mn[3][TEN];
#pragma unroll
        for (int t = 0; t < 3; ++t)
#pragma unroll
            for (int j = 0; j < TEN; ++j) mn[t][j] = 0.0f;

#pragma unroll
        for (int a = 0; a < TEN; ++a) {
            const float4 b0 = reinterpret_cast<const float4*>(wc + a * 12)[0];
            const float4 b1 = reinterpret_cast<const float4*>(wc + a * 12)[1];
            const float2 b2 = reinterpret_cast<const float2*>(wc + a * 12 + 8)[0];
#pragma unroll
            for (int t = 0; t < 3; ++t) {
                const float ma = m[t][a];
                mn[t][0] = fmaf(ma, b0.x, mn[t][0]);
                mn[t][1] = fmaf(ma, b0.y, mn[t][1]);
                mn[t][2] = fmaf(ma, b0.z, mn[t][2]);
                mn[t][3] = fmaf(ma, b0.w, mn[t][3]);
                mn[t][4] = fmaf(ma, b1.x, mn[t][4]);
                mn[t][5] = fmaf(ma, b1.y, mn[t][5]);
                mn[t][6] = fmaf(ma, b1.z, mn[t][6]);
                mn[t][7] = fmaf(ma, b1.w, mn[t][7]);
                mn[t][8] = fmaf(ma, b2.x, mn[t][8]);
                mn[t][9] = fmaf(ma, b2.y, mn[t][9]);
            }
        }
#pragma unroll
        for (int t = 0; t < 3; ++t)
#pragma unroll
            for (int j = 0; j < TEN; ++j) m[t][j] = mn[t][j];
        __builtin_amdgcn_wave_barrier();  // keep next writes after these reads
    }

    // Stage this chunk's M into the tree buffer (stride 120) and reduce 64 -> 1.
    __syncthreads();   // everyone done with W staging regions
    {
        float* dst = lds + cib * 120;
#pragma unroll
        for (int t = 0; t < 3; ++t) {
            const int rt = (t == 0) ? r0 : (t == 1) ? r1 : r2;
            if (t < 2 || w2) {
                float* dr = dst + rt * 12;
                reinterpret_cast<float4*>(dr)[0] = make_float4(m[t][0], m[t][1], m[t][2], m[t][3]);
                reinterpret_cast<float4*>(dr)[1] = make_float4(m[t][4], m[t][5], m[t][6], m[t][7]);
                reinterpret_cast<float2*>(dr + 8)[0] = make_float2(m[t][8], m[t][9]);
            }
        }
    }
    __syncthreads();
    tree64(lds, tid);

    // Quad 0 stores the block's product matrix.
    if (tid < 4) {
        const int sb = tid;
        const int rb = (sb == 3) ? 8 : sb * 3;
#pragma unroll
        for (int t = 0; t < 3; ++t) {
            const int rt = (t == 0) ? rb : (t == 1) ? rb + 1 : ((rb + 2 > 9) ? 9 : rb + 2);
            if (t < 2 || sb < 2) {
                const float* src = lds + rt * 12;
                float* dr = outBlk + (size_t)blockIdx.x * 100 + rt * TEN;
#pragma unroll
                for (int j = 0; j < TEN; ++j) dr[j] = src[j];
            }
        }
    }
}

// ---------------------------------------------------------------------------
// Final: one block. 64 quads chain 4 consecutive block-matrices each
// (256 -> 64), tree-reduce 64 -> 1 in LDS, then apply start/accept.
// ---------------------------------------------------------------------------
__global__ void automaton_final(const float* __restrict__ blkM,
                                const float* __restrict__ start,
                                const float* __restrict__ acc,
                                float* __restrict__ outv)
{
    __shared__ __align__(16) float lds[7680];
    __shared__ float sv[TEN];
    const int tid = threadIdx.x;
    const int q   = tid >> 2;
    const int sub = tid & 3;
    const int rbase = (sub == 3) ? 8 : sub * 3;
    const int r0 = rbase, r1 = rbase + 1;
    const int r2 = (rbase + 2 > 9) ? 9 : rbase + 2;
    const bool w2 = (sub < 2);
    const int rr0 = r0, rr1 = r1, rr2 = r2;

    // a = this lane's rows of blkM[4q]
    float a[3][TEN];
    {
        const int rr[3] = {rr0, rr1, rr2};
        const float* A0 = blkM + (size_t)(4 * q) * 100;
#pragma unroll
        for (int t = 0; t < 3; ++t) {
            const float2* pp = reinterpret_cast<const float2*>(A0 + rr[t] * TEN);
            const float2 a0 = pp[0], a1 = pp[1], a2 = pp[2], a3 = pp[3], a4 = pp[4];
            a[t][0]=a0.x; a[t][1]=a0.y; a[t][2]=a1.x; a[t][3]=a1.y; a[t][4]=a2.x;
            a[t][5]=a2.y; a[t][6]=a3.x; a[t][7]=a3.y; a[t][8]=a4.x; a[t][9]=a4.y;
        }
    }
#pragma unroll 1
    for (int i = 1; i < 4; ++i) {
        const float* B = blkM + (size_t)(4 * q + i) * 100;
        float c[3][TEN];
#pragma unroll
        for (int t = 0; t < 3; ++t)
#pragma unroll
            for (int j = 0; j < TEN; ++j) c[t][j] = 0.0f;
#pragma unroll
        for (int aa = 0; aa < TEN; ++aa) {
            const float2* br = reinterpret_cast<const float2*>(B + aa * TEN);
            const float2 b0 = br[0], b1 = br[1], b2 = br[2], b3 = br[3], b4 = br[4];
#pragma unroll
            for (int t = 0; t < 3; ++t) {
                const float ma = a[t][aa];
                c[t][0] = fmaf(ma, b0.x, c[t][0]);
                c[t][1] = fmaf(ma, b0.y, c[t][1]);
                c[t][2] = fmaf(ma, b1.x, c[t][2]);
                c[t][3] = fmaf(ma, b1.y, c[t][3]);
                c[t][4] = fmaf(ma, b2.x, c[t][4]);
                c[t][5] = fmaf(ma, b2.y, c[t][5]);
                c[t][6] = fmaf(ma, b3.x, c[t][6]);
                c[t][7] = fmaf(ma, b3.y, c[t][7]);
                c[t][8] = fmaf(ma, b4.x, c[t][8]);
                c[t][9] = fmaf(ma, b4.y, c[t][9]);
            }
        }
#pragma unroll
        for (int t = 0; t < 3; ++t)
#pragma unroll
            for (int j = 0; j < TEN; ++j) a[t][j] = c[t][j];
    }
    // stage to LDS slot q
    {
        float* dst = lds + q * 120;
#pragma unroll
        for (int t = 0; t < 3; ++t) {
            const int rt = (t == 0) ? rr0 : (t == 1) ? rr1 : rr2;
            if (t < 2 || w2) {
                float* dr = dst + rt * 12;
                reinterpret_cast<float4*>(dr)[0] = make_float4(a[t][0], a[t][1], a[t][2], a[t][3]);
                reinterpret_cast<float4*>(dr)[1] = make_float4(a[t][4], a[t][5], a[t][6], a[t][7]);
                reinterpret_cast<float2*>(dr + 8)[0] = make_float2(a[t][8], a[t][9]);
            }
        }
    }
    __syncthreads();
    tree64(lds, tid);

    if (tid < TEN) {
        const int j = tid;
        float v = 0.0f;
#pragma unroll
        for (int r = 0; r < TEN; ++r) v = fmaf(start[r], lds[r * 12 + j], v);
        sv[j] = v;
    }
    __syncthreads();
    if (tid == 0) {
        float o0 = 0.0f, o1 = 0.0f;
#pragma unroll
        for (int j = 0; j < TEN; ++j) {
            o0 = fmaf(sv[j], acc[2 * j + 0], o0);
            o1 = fmaf(sv[j], acc[2 * j + 1], o1);
        }
        outv[0] = o0;
        outv[1] = o1;
    }
}

extern "C" void kernel_launch(void* const* d_in, const int* in_sizes, int n_in,
                              void* d_out, int out_size, void* d_ws, size_t ws_size,
                              hipStream_t stream)
{
    const float* x     = (const float*)d_in[0];
    const float* P     = (const float*)d_in[1];
    const float* start = (const float*)d_in[2];
    const float* acc   = (const float*)d_in[3];
    float* out         = (float*)d_out;

    const long long T = (long long)in_sizes[0] / TEN;  // 2,097,152
    const int L = (int)(T / 16384);                    // 128 steps per chunk

    float* blkM = (float*)d_ws;                        // [256][10][10]

    automaton_chunks<<<256, 256, 0, stream>>>(x, P, blkM, L);
    automaton_final<<<1, 256, 0, stream>>>(blkM, start, acc, out);
}

// Round 5
// 266.687 us; speedup vs baseline: 1.1660x; 1.1660x over previous
//
#include <hip/hip_runtime.h>

#define TEN 10

// ---------------------------------------------------------------------------
// Phase A: 5 lanes per chunk, COLUMN ownership. Lane sub owns columns
// j0=2*sub, j1=2*sub+1 of both W_t and M. P-slice p[c][k][a] = P[k][a][j]
// is 200 floats (fits the 256-arch-VGPR/wave HW wall that sank the 4-lane
// row scheme: 360 live -> AGPR spill moves, VALUBusy 51%).
// Per step: publish own M columns to LDS (shared operand is M_t, known at
// step START), build W columns locally (200 FMA overlap the LDS read
// latency), then M_new[:,own] = M_t @ W[:,own] via streamed column reads.
// LDS: M col-major, column stride 12 floats (48 B -> every column 16B-aligned
// -> pure b128/b64), chunk slot stride 132 floats (bank offset 4g mod 32 ->
// <=2-way across the 12 groups of a wave = free per m136).
// No __syncthreads in the main loop: sharing is intra-wave (in-order DS pipe).
// 12 chunks/wave, 48/block, grid=256 (1 block/CU, 1 wave/SIMD).
// ---------------------------------------------------------------------------
__global__ __attribute__((amdgpu_flat_work_group_size(256, 256),
                          amdgpu_waves_per_eu(1, 1)))
void automaton_chunks(const float* __restrict__ x, const float* __restrict__ P,
                      float* __restrict__ outBlk, long long T, int C)
{
    // main loop: 48 slots * 132 floats = 6336. tree: T0=48*120 @0, T1 @5760.
    __shared__ __align__(16) float lds[8704];

    const int tid  = threadIdx.x;
    const int wave = tid >> 6;
    const int lane = tid & 63;
    const int grp  = lane / 5;        // 0..11 active, 12 => idle lanes 60..63
    const int sub  = lane % 5;
    const bool active = (grp < 12);
    const int cib  = wave * 12 + grp; // chunk within block 0..47
    const int j0 = 2 * sub, j1 = j0 + 1;

    float p[2][TEN][TEN];             // p[c][k][a] = P[k][a][2sub+c]
    float m[TEN][2];                  // own columns of M
    long long Lc = 0;
    const float2* xp = nullptr;
    float* slot = lds + (active ? cib : 0) * 132;

    if (active) {
        const long long chunk = (long long)blockIdx.x * 48 + cib;
        const long long s0 = chunk * T / C;
        const long long s1 = (chunk + 1) * T / C;
        Lc = s1 - s0;
        xp = reinterpret_cast<const float2*>(x) + s0 * 5;
#pragma unroll
        for (int k = 0; k < TEN; ++k)
#pragma unroll
            for (int a = 0; a < TEN; ++a) {
                const float2 v = *reinterpret_cast<const float2*>(P + k * 100 + a * TEN + j0);
                p[0][k][a] = v.x;
                p[1][k][a] = v.y;
            }
#pragma unroll
        for (int r = 0; r < TEN; ++r) {
            m[r][0] = (r == j0) ? 1.0f : 0.0f;
            m[r][1] = (r == j1) ? 1.0f : 0.0f;
        }
    }

    float2 nx0, nx1, nx2, nx3, nx4;
    if (active) { nx0 = xp[0]; nx1 = xp[1]; nx2 = xp[2]; nx3 = xp[3]; nx4 = xp[4]; xp += 5; }

    if (active) {
#pragma unroll 1
        for (long long s = 0; s < Lc; ++s) {
            const float xv[TEN] = {nx0.x, nx0.y, nx1.x, nx1.y, nx2.x,
                                   nx2.y, nx3.x, nx3.y, nx4.x, nx4.y};
            if (s + 1 < Lc) {
                nx0 = xp[0]; nx1 = xp[1]; nx2 = xp[2]; nx3 = xp[3]; nx4 = xp[4];
                xp += 5;
            }

            // 1) publish own columns of M_t (col c at offset (2sub+c)*12)
            {
                float* c0 = slot + j0 * 12;
                reinterpret_cast<float4*>(c0)[0] = make_float4(m[0][0], m[1][0], m[2][0], m[3][0]);
                reinterpret_cast<float4*>(c0)[1] = make_float4(m[4][0], m[5][0], m[6][0], m[7][0]);
                reinterpret_cast<float2*>(c0 + 8)[0] = make_float2(m[8][0], m[9][0]);
                float* c1 = slot + j1 * 12;
                reinterpret_cast<float4*>(c1)[0] = make_float4(m[0][1], m[1][1], m[2][1], m[3][1]);
                reinterpret_cast<float4*>(c1)[1] = make_float4(m[4][1], m[5][1], m[6][1], m[7][1]);
                reinterpret_cast<float2*>(c1 + 8)[0] = make_float2(m[8][1], m[9][1]);
            }
            __builtin_amdgcn_wave_barrier();   // write -> read order (in-order DS pipe)

            // 2) build own W columns: w_c[a] = sum_k xv[k] * p[c][k][a]
            //    (independent of the LDS reads -> overlaps their latency)
            float w0[TEN], w1[TEN];
#pragma unroll
            for (int a = 0; a < TEN; ++a) {
                float a0 = xv[0] * p[0][0][a];
                float a1 = xv[0] * p[1][0][a];
#pragma unroll
                for (int k = 1; k < TEN; ++k) {
                    a0 = fmaf(xv[k], p[0][k][a], a0);
                    a1 = fmaf(xv[k], p[1][k][a], a1);
                }
                w0[a] = a0; w1[a] = a1;
            }

            // 3) M_new[:,own] = M_t @ W[:,own] — stream M columns from LDS
            float mn[TEN][2];
#pragma unroll
            for (int r = 0; r < TEN; ++r) { mn[r][0] = 0.0f; mn[r][1] = 0.0f; }
#pragma unroll
            for (int a = 0; a < TEN; ++a) {
                const float4 v0 = reinterpret_cast<const float4*>(slot + a * 12)[0];
                const float4 v1 = reinterpret_cast<const float4*>(slot + a * 12)[1];
                const float2 v2 = reinterpret_cast<const float2*>(slot + a * 12 + 8)[0];
                const float ca[TEN] = {v0.x, v0.y, v0.z, v0.w, v1.x, v1.y, v1.z, v1.w, v2.x, v2.y};
                const float wa0 = w0[a], wa1 = w1[a];
#pragma unroll
                for (int r = 0; r < TEN; ++r) {
                    mn[r][0] = fmaf(ca[r], wa0, mn[r][0]);
                    mn[r][1] = fmaf(ca[r], wa1, mn[r][1]);
                }
            }
#pragma unroll
            for (int r = 0; r < TEN; ++r) { m[r][0] = mn[r][0]; m[r][1] = mn[r][1]; }
            __builtin_amdgcn_wave_barrier();   // reads before next step's writes
        }
    }

    // ---- in-block ordered tree: 48 chunk matrices -> 1 --------------------
    __syncthreads();                  // main-loop LDS region now dead
    if (active) {
        // stage own columns into ROW-major tree slot cib (stride 120, rows 12)
        float* t = lds + cib * 120;
#pragma unroll
        for (int r = 0; r < TEN; ++r) {
            t[r * 12 + j0] = m[r][0];
            t[r * 12 + j1] = m[r][1];
        }
    }
    __syncthreads();

    // thread-per-row tree products: 48 -> 24 -> 12 -> 6 -> 3 (ping-pong)
    {
        const float* src = lds;
        float* dst = lds + 5760;
        int n = 48;
        while (n > 3) {
            const int np = n >> 1;
            const int pI = tid / TEN;
            const int r  = tid % TEN;
            if (pI < np) {
                const float* A = src + (2 * pI) * 120;
                const float* B = src + (2 * pI + 1) * 120;
                float ar[TEN];
#pragma unroll
                for (int j = 0; j < TEN; ++j) ar[j] = A[r * 12 + j];
                float c[TEN] = {0, 0, 0, 0, 0, 0, 0, 0, 0, 0};
#pragma unroll
                for (int a = 0; a < TEN; ++a) {
                    const float ma = ar[a];
#pragma unroll
                    for (int j = 0; j < TEN; ++j) c[j] = fmaf(ma, B[a * 12 + j], c[j]);
                }
                float* C = dst + pI * 120;
#pragma unroll
                for (int j = 0; j < TEN; ++j) C[r * 12 + j] = c[j];
            }
            __syncthreads();
            const float* ts = src; src = dst; dst = const_cast<float*>(ts);
            n = np;
        }
        // 3 matrices left in src (== lds). Serial: (M0*M1)*M2 by 10 threads.
        if (tid < TEN) {
            const int r = tid;
            float ar[TEN];
#pragma unroll
            for (int j = 0; j < TEN; ++j) ar[j] = src[r * 12 + j];
            float c[TEN] = {0, 0, 0, 0, 0, 0, 0, 0, 0, 0};
#pragma unroll
            for (int a = 0; a < TEN; ++a) {
                const float ma = ar[a];
#pragma unroll
                for (int j = 0; j < TEN; ++j) c[j] = fmaf(ma, src[120 + a * 12 + j], c[j]);
            }
#pragma unroll
            for (int j = 0; j < TEN; ++j) lds[5760 + r * 12 + j] = c[j];
        }
        __syncthreads();
        if (tid < TEN) {
            const int r = tid;
            float c[TEN] = {0, 0, 0, 0, 0, 0, 0, 0, 0, 0};
#pragma unroll
            for (int a = 0; a < TEN; ++a) {
                const float ma = lds[5760 + r * 12 + a];
#pragma unroll
                for (int j = 0; j < TEN; ++j) c[j] = fmaf(ma, src[240 + a * 12 + j], c[j]);
            }
            float* dr = outBlk + (size_t)blockIdx.x * 100 + r * TEN;
#pragma unroll
            for (int j = 0; j < TEN; ++j) dr[j] = c[j];
        }
    }
}

// ---------------------------------------------------------------------------
// tree64 helper for the final kernel (row-major slots, stride 120).
// Quad row partition {0,1,2},{3,4,5},{6,7,(dup)},{8,9,(dup)}.
// ---------------------------------------------------------------------------
__device__ __forceinline__ void tree64(float* lds, int tid)
{
    const int q     = tid >> 2;
    const int sub   = tid & 3;
    const int rbase = (sub == 3) ? 8 : sub * 3;
    const int r0 = rbase, r1 = rbase + 1;
    const int r2 = (rbase + 2 > 9) ? 9 : rbase + 2;
    const bool w2 = (sub < 2);

    for (int np = 32; np >= 1; np >>= 1) {
        float c[3][TEN];
        if (q < np) {
            const float* A = lds + (2 * q) * 120;
            const float* B = lds + (2 * q + 1) * 120;
            float ar[3][TEN];
#pragma unroll
            for (int t = 0; t < 3; ++t) {
                const int rt = (t == 0) ? r0 : (t == 1) ? r1 : r2;
                const float4 a0 = reinterpret_cast<const float4*>(A + rt * 12)[0];
                const float4 a1 = reinterpret_cast<const float4*>(A + rt * 12)[1];
                const float2 a2 = reinterpret_cast<const float2*>(A + rt * 12 + 8)[0];
                ar[t][0]=a0.x; ar[t][1]=a0.y; ar[t][2]=a0.z; ar[t][3]=a0.w;
                ar[t][4]=a1.x; ar[t][5]=a1.y; ar[t][6]=a1.z; ar[t][7]=a1.w;
                ar[t][8]=a2.x; ar[t][9]=a2.y;
#pragma unroll
                for (int j = 0; j < TEN; ++j) c[t][j] = 0.0f;
            }
#pragma unroll
            for (int a = 0; a < TEN; ++a) {
                const float4 b0 = reinterpret_cast<const float4*>(B + a * 12)[0];
                const float4 b1 = reinterpret_cast<const float4*>(B + a * 12)[1];
                const float2 b2 = reinterpret_cast<const float2*>(B + a * 12 + 8)[0];
                const float br[TEN] = {b0.x,b0.y,b0.z,b0.w,b1.x,b1.y,b1.z,b1.w,b2.x,b2.y};
#pragma unroll
                for (int t = 0; t < 3; ++t) {
                    const float ma = ar[t][a];
#pragma unroll
                    for (int j = 0; j < TEN; ++j) c[t][j] = fmaf(ma, br[j], c[t][j]);
                }
            }
        }
        __syncthreads();
        if (q < np) {
            float* C = lds + q * 120;
#pragma unroll
            for (int t = 0; t < 3; ++t) {
                const int rt = (t == 0) ? r0 : (t == 1) ? r1 : r2;
                if (t < 2 || w2) {
                    float* cr = C + rt * 12;
                    reinterpret_cast<float4*>(cr)[0] = make_float4(c[t][0], c[t][1], c[t][2], c[t][3]);
                    reinterpret_cast<float4*>(cr)[1] = make_float4(c[t][4], c[t][5], c[t][6], c[t][7]);
                    reinterpret_cast<float2*>(cr + 8)[0] = make_float2(c[t][8], c[t][9]);
                }
            }
        }
        __syncthreads();
    }
}

// ---------------------------------------------------------------------------
// Final: one block. 64 quads chain 4 consecutive block-matrices (256 -> 64),
// tree64 -> 1, then apply start/accept.
// ---------------------------------------------------------------------------
__global__ void automaton_final(const float* __restrict__ blkM,
                                const float* __restrict__ start,
                                const float* __restrict__ acc,
                                float* __restrict__ outv)
{
    __shared__ __align__(16) float lds[7680];
    __shared__ float sv[TEN];
    const int tid = threadIdx.x;
    const int q   = tid >> 2;
    const int sub = tid & 3;
    const int rbase = (sub == 3) ? 8 : sub * 3;
    const int rr0 = rbase, rr1 = rbase + 1;
    const int rr2 = (rbase + 2 > 9) ? 9 : rbase + 2;
    const bool w2 = (sub < 2);

    float a[3][TEN];
    {
        const int rr[3] = {rr0, rr1, rr2};
        const float* A0 = blkM + (size_t)(4 * q) * 100;
#pragma unroll
        for (int t = 0; t < 3; ++t) {
            const float2* pp = reinterpret_cast<const float2*>(A0 + rr[t] * TEN);
            const float2 a0 = pp[0], a1 = pp[1], a2 = pp[2], a3 = pp[3], a4 = pp[4];
            a[t][0]=a0.x; a[t][1]=a0.y; a[t][2]=a1.x; a[t][3]=a1.y; a[t][4]=a2.x;
            a[t][5]=a2.y; a[t][6]=a3.x; a[t][7]=a3.y; a[t][8]=a4.x; a[t][9]=a4.y;
        }
    }
#pragma unroll 1
    for (int i = 1; i < 4; ++i) {
        const float* B = blkM + (size_t)(4 * q + i) * 100;
        float c[3][TEN];
#pragma unroll
        for (int t = 0; t < 3; ++t)
#pragma unroll
            for (int j = 0; j < TEN; ++j) c[t][j] = 0.0f;
#pragma unroll
        for (int aa = 0; aa < TEN; ++aa) {
            const float2* br = reinterpret_cast<const float2*>(B + aa * TEN);
            const float2 b0 = br[0], b1 = br[1], b2 = br[2], b3 = br[3], b4 = br[4];
            const float bv[TEN] = {b0.x,b0.y,b1.x,b1.y,b2.x,b2.y,b3.x,b3.y,b4.x,b4.y};
#pragma unroll
            for (int t = 0; t < 3; ++t) {
                const float ma = a[t][aa];
#pragma unroll
                for (int j = 0; j < TEN; ++j) c[t][j] = fmaf(ma, bv[j], c[t][j]);
            }
        }
#pragma unroll
        for (int t = 0; t < 3; ++t)
#pragma unroll
            for (int j = 0; j < TEN; ++j) a[t][j] = c[t][j];
    }
    {
        float* dst = lds + q * 120;
#pragma unroll
        for (int t = 0; t < 3; ++t) {
            const int rt = (t == 0) ? rr0 : (t == 1) ? rr1 : rr2;
            if (t < 2 || w2) {
                float* dr = dst + rt * 12;
                reinterpret_cast<float4*>(dr)[0] = make_float4(a[t][0], a[t][1], a[t][2], a[t][3]);
                reinterpret_cast<float4*>(dr)[1] = make_float4(a[t][4], a[t][5], a[t][6], a[t][7]);
                reinterpret_cast<float2*>(dr + 8)[0] = make_float2(a[t][8], a[t][9]);
            }
        }
    }
    __syncthreads();
    tree64(lds, tid);

    if (tid < TEN) {
        const int j = tid;
        float v = 0.0f;
#pragma unroll
        for (int r = 0; r < TEN; ++r) v = fmaf(start[r], lds[r * 12 + j], v);
        sv[j] = v;
    }
    __syncthreads();
    if (tid == 0) {
        float o0 = 0.0f, o1 = 0.0f;
#pragma unroll
        for (int j = 0; j < TEN; ++j) {
            o0 = fmaf(sv[j], acc[2 * j + 0], o0);
            o1 = fmaf(sv[j], acc[2 * j + 1], o1);
        }
        outv[0] = o0;
        outv[1] = o1;
    }
}

extern "C" void kernel_launch(void* const* d_in, const int* in_sizes, int n_in,
                              void* d_out, int out_size, void* d_ws, size_t ws_size,
                              hipStream_t stream)
{
    const float* x     = (const float*)d_in[0];
    const float* P     = (const float*)d_in[1];
    const float* start = (const float*)d_in[2];
    const float* acc   = (const float*)d_in[3];
    float* out         = (float*)d_out;

    const long long T = (long long)in_sizes[0] / TEN;  // 2,097,152 steps
    const int C = 12288;                               // 48 chunks x 256 blocks

    float* blkM = (float*)d_ws;                        // [256][10][10]

    automaton_chunks<<<256, 256, 0, stream>>>(x, P, blkM, T, C);
    automaton_final<<<1, 256, 0, stream>>>(blkM, start, acc, out);
}